// Round 2
// baseline (2053.139 us; speedup 1.0000x reference)
//
#include <hip/hip_runtime.h>
#include <math.h>

#define H 8
#define FD 128
#define SCALE 0.25f

typedef __attribute__((ext_vector_type(8))) short bf16x8;
typedef __attribute__((ext_vector_type(4))) float f32x4;

__device__ __forceinline__ unsigned short bf_rne(float f) {
    unsigned u = __float_as_uint(f);
    u += 0x7FFFu + ((u >> 16) & 1u);
    return (unsigned short)(u >> 16);
}
__device__ __forceinline__ float bf_to_f(unsigned short s) {
    return __uint_as_float(((unsigned)s) << 16);
}
__device__ __forceinline__ bf16x8 cvt8(const float* __restrict__ p) {
    float4 a = *(const float4*)p;
    float4 b = *(const float4*)(p + 4);
    bf16x8 r;
    r[0] = bf_rne(a.x); r[1] = bf_rne(a.y); r[2] = bf_rne(a.z); r[3] = bf_rne(a.w);
    r[4] = bf_rne(b.x); r[5] = bf_rne(b.y); r[6] = bf_rne(b.z); r[7] = bf_rne(b.w);
    return r;
}

// ---- one-time weight conversion fp32 -> bf16 (4 x 128x128) ----
__global__ __launch_bounds__(256) void prep_kernel(
    const float* __restrict__ Wq, const float* __restrict__ Wk,
    const float* __restrict__ Wv, const float* __restrict__ Wo,
    unsigned short* __restrict__ oq, unsigned short* __restrict__ ok,
    unsigned short* __restrict__ ov, unsigned short* __restrict__ oo) {
    int i = blockIdx.x * 256 + threadIdx.x;  // 0..4095 float4 groups
    const float* src[4] = {Wq, Wk, Wv, Wo};
    unsigned short* dstp[4] = {oq, ok, ov, oo};
#pragma unroll
    for (int m = 0; m < 4; ++m) {
        float4 w = ((const float4*)src[m])[i];
        ushort4 p = make_ushort4(bf_rne(w.x), bf_rne(w.y), bf_rne(w.z), bf_rne(w.w));
        *(ushort4*)(dstp[m] + i * 4) = p;
    }
}

// ---- fused q (bf16 out) + v (fp32 out) projection, MFMA ----
__global__ __launch_bounds__(256) void qv_kernel(
    const float* __restrict__ X, const unsigned short* __restrict__ Wqb,
    const unsigned short* __restrict__ Wvb, const float* __restrict__ bq,
    const float* __restrict__ bv, unsigned short* __restrict__ qb,
    float* __restrict__ v, int Nrows) {
    const int t = threadIdx.x;
    const int lane = t & 63, wid = t >> 6;
    const int lm = lane & 15, lq = lane >> 4;
    const int r0 = blockIdx.x * 128 + wid * 32;

    bf16x8 a[2][4];
#pragma unroll
    for (int mt = 0; mt < 2; ++mt)
#pragma unroll
        for (int s = 0; s < 4; ++s) {
            int r = r0 + mt * 16 + lm;
            if (r >= Nrows) r = Nrows - 1;
            a[mt][s] = cvt8(X + (size_t)r * FD + s * 32 + lq * 8);
        }
#pragma unroll
    for (int g = 0; g < 2; ++g) {
        const unsigned short* Wb = g ? Wvb : Wqb;
        const float* bias = g ? bv : bq;
        f32x4 acc[2][8];
#pragma unroll
        for (int nt = 0; nt < 8; ++nt) {
            float b = bias[nt * 16 + lm];
#pragma unroll
            for (int mt = 0; mt < 2; ++mt) {
                acc[mt][nt][0] = b; acc[mt][nt][1] = b;
                acc[mt][nt][2] = b; acc[mt][nt][3] = b;
            }
        }
#pragma unroll
        for (int s = 0; s < 4; ++s)
#pragma unroll
            for (int nt = 0; nt < 8; ++nt) {
                bf16x8 bf = *(const bf16x8*)(Wb + (nt * 16 + lm) * FD + s * 32 + lq * 8);
#pragma unroll
                for (int mt = 0; mt < 2; ++mt)
                    acc[mt][nt] = __builtin_amdgcn_mfma_f32_16x16x32_bf16(
                        a[mt][s], bf, acc[mt][nt], 0, 0, 0);
            }
#pragma unroll
        for (int mt = 0; mt < 2; ++mt)
#pragma unroll
            for (int nt = 0; nt < 8; ++nt)
#pragma unroll
                for (int r = 0; r < 4; ++r) {
                    int row = r0 + mt * 16 + lq * 4 + r;
                    if (row >= Nrows) continue;
                    int col = nt * 16 + lm;
                    if (g == 0)
                        qb[(size_t)row * FD + col] = bf_rne(acc[mt][nt][r]);
                    else
                        v[(size_t)row * FD + col] = acc[mt][nt][r];
                }
    }
}

// ---- k projection GEMM only: kb = bf16(edge_h @ Wk.T + bk) ----
__global__ __launch_bounds__(256) void kproj_kernel(
    const float* __restrict__ X, const unsigned short* __restrict__ Wkb,
    const float* __restrict__ bk, unsigned short* __restrict__ kb, int Nrows) {
    const int t = threadIdx.x;
    const int lane = t & 63, wid = t >> 6;
    const int lm = lane & 15, lq = lane >> 4;
    const int r0 = blockIdx.x * 128 + wid * 32;

    bf16x8 a[2][4];
#pragma unroll
    for (int mt = 0; mt < 2; ++mt)
#pragma unroll
        for (int s = 0; s < 4; ++s) {
            int r = r0 + mt * 16 + lm;
            if (r >= Nrows) r = Nrows - 1;
            a[mt][s] = cvt8(X + (size_t)r * FD + s * 32 + lq * 8);
        }
    f32x4 acc[2][8];
#pragma unroll
    for (int nt = 0; nt < 8; ++nt) {
        float b = bk[nt * 16 + lm];
#pragma unroll
        for (int mt = 0; mt < 2; ++mt) {
            acc[mt][nt][0] = b; acc[mt][nt][1] = b;
            acc[mt][nt][2] = b; acc[mt][nt][3] = b;
        }
    }
#pragma unroll
    for (int s = 0; s < 4; ++s)
#pragma unroll
        for (int nt = 0; nt < 8; ++nt) {
            bf16x8 bf = *(const bf16x8*)(Wkb + (nt * 16 + lm) * FD + s * 32 + lq * 8);
#pragma unroll
            for (int mt = 0; mt < 2; ++mt)
                acc[mt][nt] = __builtin_amdgcn_mfma_f32_16x16x32_bf16(
                    a[mt][s], bf, acc[mt][nt], 0, 0, 0);
        }
#pragma unroll
    for (int mt = 0; mt < 2; ++mt)
#pragma unroll
        for (int nt = 0; nt < 8; ++nt)
#pragma unroll
            for (int r = 0; r < 4; ++r) {
                int row = r0 + mt * 16 + lq * 4 + r;
                if (row >= Nrows) continue;
                int col = nt * 16 + lm;
                kb[(size_t)row * FD + col] = bf_rne(acc[mt][nt][r]);
            }
}

// ---- high-occupancy attention: dots + exp + 6 atomics into [H][N] ----
// one thread per (edge-in-chunk, head); 8 consecutive lanes share an edge
__global__ __launch_bounds__(256) void attn_kernel(
    const unsigned short* __restrict__ kb, const unsigned short* __restrict__ qb,
    const int* __restrict__ src, const int* __restrict__ dst,
    const float* __restrict__ distance, const float* __restrict__ lam,
    float* __restrict__ den1, float* __restrict__ den2,
    float* __restrict__ den3, float* __restrict__ sc1,
    float* __restrict__ sc2, float* __restrict__ sc3, int Ec, int N) {
    int p = blockIdx.x * 256 + threadIdx.x;
    if (p >= Ec * H) return;
    int el = p >> 3, h = p & 7;
    int si = src[el], di = dst[el];
    const unsigned short* kp  = kb + (size_t)el * FD + h * 16;
    const unsigned short* qsp = qb + (size_t)si * FD + h * 16;
    const unsigned short* qdp = qb + (size_t)di * FD + h * 16;
    bf16x8 k0  = *(const bf16x8*)kp;
    bf16x8 k1  = *(const bf16x8*)(kp + 8);
    bf16x8 qs0 = *(const bf16x8*)qsp;
    bf16x8 qs1 = *(const bf16x8*)(qsp + 8);
    bf16x8 qd0 = *(const bf16x8*)qdp;
    bf16x8 qd1 = *(const bf16x8*)(qdp + 8);
    float pin = 0.f, pot = 0.f, pdg = 0.f;
#pragma unroll
    for (int j = 0; j < 8; ++j) {
        float qsf = bf_to_f((unsigned short)qs0[j]);
        float qdf = bf_to_f((unsigned short)qd0[j]);
        float kf  = bf_to_f((unsigned short)k0[j]);
        pin += qsf * kf; pot += qdf * kf; pdg += qsf * qdf;
    }
#pragma unroll
    for (int j = 0; j < 8; ++j) {
        float qsf = bf_to_f((unsigned short)qs1[j]);
        float qdf = bf_to_f((unsigned short)qd1[j]);
        float kf  = bf_to_f((unsigned short)k1[j]);
        pin += qsf * kf; pot += qdf * kf; pdg += qsf * qdf;
    }
    float att = __expf(lam[0] * __logf(distance[el]));
    float e1 = __expf(pin * SCALE);
    float e2 = __expf(pot * SCALE);
    float e3 = __expf(pdg * SCALE);
    int nb = h * N + di;  // [H][N] layout: lanes of one edge hit 8 far-apart lines
    atomicAdd(den1 + nb, e1); atomicAdd(sc1 + nb, e1 * att);
    atomicAdd(den2 + nb, e2); atomicAdd(sc2 + nb, e2 * att);
    atomicAdd(den3 + nb, e3); atomicAdd(sc3 + nb, e3 * att);
}

// ---- FALLBACK (proven round-(-1) path): fused edge kernel with LDS k tile.
// Used only if workspace has no room for the chunked kb buffer. ----
__global__ __launch_bounds__(256) void edge_kernel(
    const float* __restrict__ eh, const unsigned short* __restrict__ Wkb,
    const float* __restrict__ bk, const unsigned short* __restrict__ qb,
    const int* __restrict__ src, const int* __restrict__ dst,
    const float* __restrict__ distance, const float* __restrict__ lam,
    float* __restrict__ den1, float* __restrict__ den2,
    float* __restrict__ den3, float* __restrict__ sc1,
    float* __restrict__ sc2, float* __restrict__ sc3, int E, int N) {
    __shared__ unsigned short lK[128 * 128];
    const int t = threadIdx.x;
    const int e0 = blockIdx.x * 128;
    const int lane = t & 63, wid = t >> 6;
    const int lm = lane & 15, lq = lane >> 4;
    const int wm = wid * 32;

    bf16x8 a[2][4];
#pragma unroll
    for (int mt = 0; mt < 2; ++mt)
#pragma unroll
        for (int s = 0; s < 4; ++s) {
            int e = e0 + wm + mt * 16 + lm;
            if (e >= E) e = E - 1;
            a[mt][s] = cvt8(eh + (size_t)e * FD + s * 32 + lq * 8);
        }
    f32x4 acc[2][8];
#pragma unroll
    for (int nt = 0; nt < 8; ++nt) {
        float b = bk[nt * 16 + lm];
#pragma unroll
        for (int mt = 0; mt < 2; ++mt) {
            acc[mt][nt][0] = b; acc[mt][nt][1] = b;
            acc[mt][nt][2] = b; acc[mt][nt][3] = b;
        }
    }
#pragma unroll
    for (int s = 0; s < 4; ++s)
#pragma unroll
        for (int nt = 0; nt < 8; ++nt) {
            bf16x8 bf = *(const bf16x8*)(Wkb + (nt * 16 + lm) * FD + s * 32 + lq * 8);
#pragma unroll
            for (int mt = 0; mt < 2; ++mt)
                acc[mt][nt] = __builtin_amdgcn_mfma_f32_16x16x32_bf16(
                    a[mt][s], bf, acc[mt][nt], 0, 0, 0);
        }
#pragma unroll
    for (int mt = 0; mt < 2; ++mt)
#pragma unroll
        for (int nt = 0; nt < 8; ++nt)
#pragma unroll
            for (int r = 0; r < 4; ++r) {
                int m = wm + mt * 16 + lq * 4 + r;
                int n = nt * 16 + lm;
                int swb = (n >> 3) ^ (m & 7);
                lK[m * 128 + swb * 8 + (n & 7)] = bf_rne(acc[mt][nt][r]);
            }
    __syncthreads();

    const float lamv = lam[0];
#pragma unroll
    for (int i = 0; i < 4; ++i) {
        int p = i * 256 + t;
        int el = p >> 3, h = p & 7;
        int e = e0 + el;
        if (e >= E) continue;
        int si = src[e], di = dst[e];
        const unsigned short* qsp = qb + (size_t)si * FD + h * 16;
        const unsigned short* qdp = qb + (size_t)di * FD + h * 16;
        bf16x8 qs0 = *(const bf16x8*)qsp;
        bf16x8 qs1 = *(const bf16x8*)(qsp + 8);
        bf16x8 qd0 = *(const bf16x8*)qdp;
        bf16x8 qd1 = *(const bf16x8*)(qdp + 8);
        int swb0 = (2 * h) ^ (el & 7), swb1 = (2 * h + 1) ^ (el & 7);
        bf16x8 k0 = *(const bf16x8*)(lK + el * 128 + swb0 * 8);
        bf16x8 k1 = *(const bf16x8*)(lK + el * 128 + swb1 * 8);
        float pin = 0.f, pot = 0.f, pdg = 0.f;
#pragma unroll
        for (int j = 0; j < 8; ++j) {
            float qsf = bf_to_f((unsigned short)qs0[j]);
            float qdf = bf_to_f((unsigned short)qd0[j]);
            float kf = bf_to_f((unsigned short)k0[j]);
            pin += qsf * kf; pot += qdf * kf; pdg += qsf * qdf;
        }
#pragma unroll
        for (int j = 0; j < 8; ++j) {
            float qsf = bf_to_f((unsigned short)qs1[j]);
            float qdf = bf_to_f((unsigned short)qd1[j]);
            float kf = bf_to_f((unsigned short)k1[j]);
            pin += qsf * kf; pot += qdf * kf; pdg += qsf * qdf;
        }
        float att = __expf(lamv * __logf(distance[e]));
        float e1 = __expf(pin * SCALE);
        float e2 = __expf(pot * SCALE);
        float e3 = __expf(pdg * SCALE);
        int nb = h * N + di;
        atomicAdd(den1 + nb, e1); atomicAdd(sc1 + nb, e1 * att);
        atomicAdd(den2 + nb, e2); atomicAdd(sc2 + nb, e2 * att);
        atomicAdd(den3 + nb, e3); atomicAdd(sc3 + nb, e3 * att);
    }
}

// ---- per (node,head): ssum = s1/d1 + s2/d2 + s3/d3 (elementwise, flat) ----
__global__ __launch_bounds__(256) void combine_kernel(
    const float* __restrict__ den1, const float* __restrict__ den2,
    const float* __restrict__ den3, const float* __restrict__ sc1,
    const float* __restrict__ sc2, const float* __restrict__ sc3,
    float* __restrict__ ssum, int NH) {
    int i = blockIdx.x * 256 + threadIdx.x;
    if (i >= NH) return;
    float r = 0.f;
    float d1 = den1[i]; if (d1 != 0.f) r += sc1[i] / d1;
    float d2 = den2[i]; if (d2 != 0.f) r += sc2[i] / d2;
    float d3 = den3[i]; if (d3 != 0.f) r += sc3[i] / d3;
    ssum[i] = r;
}

// ---- out = leaky_relu( (ssum*v) @ Wo.T + bo ), MFMA; ssum is [H][N] ----
__global__ __launch_bounds__(256) void out_kernel(
    const float* __restrict__ v, const float* __restrict__ ssum,
    const unsigned short* __restrict__ Wob, const float* __restrict__ bo,
    float* __restrict__ out, int Nrows) {
    const int t = threadIdx.x;
    const int lane = t & 63, wid = t >> 6;
    const int lm = lane & 15, lq = lane >> 4;
    const int r0 = blockIdx.x * 128 + wid * 32;

    bf16x8 a[2][4];
#pragma unroll
    for (int mt = 0; mt < 2; ++mt)
#pragma unroll
        for (int s = 0; s < 4; ++s) {
            int r = r0 + mt * 16 + lm;
            if (r >= Nrows) r = Nrows - 1;
            int k0 = s * 32 + lq * 8;
            float sc = ssum[(k0 >> 4) * Nrows + r];  // [H][N]
            const float* p = v + (size_t)r * FD + k0;
            float4 x = *(const float4*)p;
            float4 y = *(const float4*)(p + 4);
            bf16x8 f;
            f[0] = bf_rne(x.x * sc); f[1] = bf_rne(x.y * sc);
            f[2] = bf_rne(x.z * sc); f[3] = bf_rne(x.w * sc);
            f[4] = bf_rne(y.x * sc); f[5] = bf_rne(y.y * sc);
            f[6] = bf_rne(y.z * sc); f[7] = bf_rne(y.w * sc);
            a[mt][s] = f;
        }
    f32x4 acc[2][8];
#pragma unroll
    for (int nt = 0; nt < 8; ++nt) {
        float b = bo[nt * 16 + lm];
#pragma unroll
        for (int mt = 0; mt < 2; ++mt) {
            acc[mt][nt][0] = b; acc[mt][nt][1] = b;
            acc[mt][nt][2] = b; acc[mt][nt][3] = b;
        }
    }
#pragma unroll
    for (int s = 0; s < 4; ++s)
#pragma unroll
        for (int nt = 0; nt < 8; ++nt) {
            bf16x8 bf = *(const bf16x8*)(Wob + (nt * 16 + lm) * FD + s * 32 + lq * 8);
#pragma unroll
            for (int mt = 0; mt < 2; ++mt)
                acc[mt][nt] = __builtin_amdgcn_mfma_f32_16x16x32_bf16(
                    a[mt][s], bf, acc[mt][nt], 0, 0, 0);
        }
#pragma unroll
    for (int mt = 0; mt < 2; ++mt)
#pragma unroll
        for (int nt = 0; nt < 8; ++nt)
#pragma unroll
            for (int r = 0; r < 4; ++r) {
                int row = r0 + mt * 16 + lq * 4 + r;
                if (row >= Nrows) continue;
                int col = nt * 16 + lm;
                float x = acc[mt][nt][r];
                out[(size_t)row * FD + col] = x > 0.f ? x : 0.1f * x;
            }
}

extern "C" void kernel_launch(void* const* d_in, const int* in_sizes, int n_in,
                              void* d_out, int out_size, void* d_ws,
                              size_t ws_size, hipStream_t stream) {
    (void)n_in; (void)out_size;
    const float* node_h   = (const float*)d_in[0];
    const float* edge_h   = (const float*)d_in[1];
    const float* distance = (const float*)d_in[2];
    const float* Wq = (const float*)d_in[3];
    const float* bq = (const float*)d_in[4];
    const float* Wk = (const float*)d_in[5];
    const float* bk = (const float*)d_in[6];
    const float* Wv = (const float*)d_in[7];
    const float* bv = (const float*)d_in[8];
    const float* Wo = (const float*)d_in[9];
    const float* bo = (const float*)d_in[10];
    const float* lam = (const float*)d_in[11];
    const int* src = (const int*)d_in[12];
    const int* dst = (const int*)d_in[13];

    int N = in_sizes[0] / FD;
    int E = in_sizes[1] / FD;
    int NH = N * H;

    char* ws = (char*)d_ws;
    unsigned short* Wqb = (unsigned short*)ws; ws += FD * FD * 2;
    unsigned short* Wkb = (unsigned short*)ws; ws += FD * FD * 2;
    unsigned short* Wvb = (unsigned short*)ws; ws += FD * FD * 2;
    unsigned short* Wob = (unsigned short*)ws; ws += FD * FD * 2;
    unsigned short* qb  = (unsigned short*)ws; ws += (size_t)N * FD * 2;
    float* v    = (float*)ws; ws += (size_t)N * FD * 4;
    char* zero_base = ws;
    float* den1 = (float*)ws; ws += (size_t)NH * 4;
    float* den2 = (float*)ws; ws += (size_t)NH * 4;
    float* den3 = (float*)ws; ws += (size_t)NH * 4;
    float* sc1  = (float*)ws; ws += (size_t)NH * 4;
    float* sc2  = (float*)ws; ws += (size_t)NH * 4;
    float* sc3  = (float*)ws; ws += (size_t)NH * 4;
    float* ssum = (float*)ws; ws += (size_t)NH * 4;
    unsigned short* kb = (unsigned short*)ws;  // chunked k buffer (bf16)

    hipMemsetAsync(zero_base, 0, (size_t)6 * NH * 4, stream);

    prep_kernel<<<16, 256, 0, stream>>>(Wq, Wk, Wv, Wo, Wqb, Wkb, Wvb, Wob);

    int nb = (N + 127) / 128;
    qv_kernel<<<nb, 256, 0, stream>>>(node_h, Wqb, Wvb, bq, bv, qb, v, N);

    // chunk size for split path: fit strictly inside remaining workspace,
    // cap at 320K edges (84 MB bf16) to stay Infinity-Cache resident
    size_t used = (size_t)(ws - (char*)d_ws);
    size_t avail = ws_size > used ? ws_size - used : 0;
    size_t cap = avail / ((size_t)FD * 2);
    size_t per = 327680;
    if (cap < per) per = cap & ~(size_t)127;

    if (per >= 128) {
        // split path: BW-bound k-projection GEMM + high-occupancy attention
        if (per > (size_t)E) per = (size_t)E;
        for (size_t s0 = 0; s0 < (size_t)E; s0 += per) {
            int ce = (int)(((size_t)E - s0) < per ? ((size_t)E - s0) : per);
            int kblocks = (ce + 127) / 128;
            kproj_kernel<<<kblocks, 256, 0, stream>>>(
                edge_h + s0 * FD, Wkb, bk, kb, ce);
            int ablocks = (int)(((long long)ce * H + 255) / 256);
            attn_kernel<<<ablocks, 256, 0, stream>>>(
                kb, qb, src + s0, dst + s0, distance + s0, lam,
                den1, den2, den3, sc1, sc2, sc3, ce, N);
        }
    } else {
        // fallback: proven fused path (no extra workspace needed)
        int ebl = (E + 127) / 128;
        edge_kernel<<<ebl, 256, 0, stream>>>(
            edge_h, Wkb, bk, qb, src, dst, distance, lam,
            den1, den2, den3, sc1, sc2, sc3, E, N);
    }

    combine_kernel<<<(NH + 255) / 256, 256, 0, stream>>>(
        den1, den2, den3, sc1, sc2, sc3, ssum, NH);

    out_kernel<<<nb, 256, 0, stream>>>(v, ssum, Wob, bo, (float*)d_out, N);
}

// Round 3
// 725.141 us; speedup vs baseline: 2.8314x; 2.8314x over previous
//
#include <hip/hip_runtime.h>
#include <math.h>

#define H 8
#define FD 128
#define SCALE 0.25f

typedef __attribute__((ext_vector_type(8))) short bf16x8;
typedef __attribute__((ext_vector_type(4))) float f32x4;

__device__ __forceinline__ unsigned short bf_rne(float f) {
    unsigned u = __float_as_uint(f);
    u += 0x7FFFu + ((u >> 16) & 1u);
    return (unsigned short)(u >> 16);
}
__device__ __forceinline__ float bf_to_f(unsigned short s) {
    return __uint_as_float(((unsigned)s) << 16);
}
__device__ __forceinline__ bf16x8 cvt8(const float* __restrict__ p) {
    float4 a = *(const float4*)p;
    float4 b = *(const float4*)(p + 4);
    bf16x8 r;
    r[0] = bf_rne(a.x); r[1] = bf_rne(a.y); r[2] = bf_rne(a.z); r[3] = bf_rne(a.w);
    r[4] = bf_rne(b.x); r[5] = bf_rne(b.y); r[6] = bf_rne(b.z); r[7] = bf_rne(b.w);
    return r;
}

// ---- one-time weight conversion fp32 -> bf16 (4 x 128x128) ----
__global__ __launch_bounds__(256) void prep_kernel(
    const float* __restrict__ Wq, const float* __restrict__ Wk,
    const float* __restrict__ Wv, const float* __restrict__ Wo,
    unsigned short* __restrict__ oq, unsigned short* __restrict__ ok,
    unsigned short* __restrict__ ov, unsigned short* __restrict__ oo) {
    int i = blockIdx.x * 256 + threadIdx.x;  // 0..4095 float4 groups
    const float* src[4] = {Wq, Wk, Wv, Wo};
    unsigned short* dstp[4] = {oq, ok, ov, oo};
#pragma unroll
    for (int m = 0; m < 4; ++m) {
        float4 w = ((const float4*)src[m])[i];
        ushort4 p = make_ushort4(bf_rne(w.x), bf_rne(w.y), bf_rne(w.z), bf_rne(w.w));
        *(ushort4*)(dstp[m] + i * 4) = p;
    }
}

// ---- fused q (bf16 out) + v (fp32 out) projection, MFMA, 64-row tile ----
// 64 rows/block (16 rows/wave): ~half the register/fragment footprint of the
// 128-row version -> higher occupancy for the same streaming traffic.
__global__ __launch_bounds__(256) void qv_kernel(
    const float* __restrict__ X, const unsigned short* __restrict__ Wqb,
    const unsigned short* __restrict__ Wvb, const float* __restrict__ bq,
    const float* __restrict__ bv, unsigned short* __restrict__ qb,
    float* __restrict__ v, int Nrows) {
    const int t = threadIdx.x;
    const int lane = t & 63, wid = t >> 6;
    const int lm = lane & 15, lq = lane >> 4;
    const int r0 = blockIdx.x * 64 + wid * 16;

    bf16x8 a[4];
#pragma unroll
    for (int s = 0; s < 4; ++s) {
        int r = r0 + lm;
        if (r >= Nrows) r = Nrows - 1;
        a[s] = cvt8(X + (size_t)r * FD + s * 32 + lq * 8);
    }
#pragma unroll
    for (int g = 0; g < 2; ++g) {
        const unsigned short* Wb = g ? Wvb : Wqb;
        const float* bias = g ? bv : bq;
        f32x4 acc[8];
#pragma unroll
        for (int nt = 0; nt < 8; ++nt) {
            float b = bias[nt * 16 + lm];
            acc[nt][0] = b; acc[nt][1] = b; acc[nt][2] = b; acc[nt][3] = b;
        }
#pragma unroll
        for (int s = 0; s < 4; ++s)
#pragma unroll
            for (int nt = 0; nt < 8; ++nt) {
                bf16x8 bf = *(const bf16x8*)(Wb + (nt * 16 + lm) * FD + s * 32 + lq * 8);
                acc[nt] = __builtin_amdgcn_mfma_f32_16x16x32_bf16(
                    a[s], bf, acc[nt], 0, 0, 0);
            }
#pragma unroll
        for (int nt = 0; nt < 8; ++nt)
#pragma unroll
            for (int r = 0; r < 4; ++r) {
                int row = r0 + lq * 4 + r;
                if (row >= Nrows) continue;
                int col = nt * 16 + lm;
                if (g == 0)
                    qb[(size_t)row * FD + col] = bf_rne(acc[nt][r]);
                else
                    v[(size_t)row * FD + col] = acc[nt][r];
            }
    }
}

// ---- fused edge kernel, 64-edge tile: k = MFMA(edge_h, Wk) -> LDS,
// then dots + exp + 6 atomics into [N][H] (proven merge-friendly layout) ----
__global__ __launch_bounds__(256) void edge_kernel(
    const float* __restrict__ eh, const unsigned short* __restrict__ Wkb,
    const float* __restrict__ bk, const unsigned short* __restrict__ qb,
    const int* __restrict__ src, const int* __restrict__ dst,
    const float* __restrict__ distance, const float* __restrict__ lam,
    float* __restrict__ den1, float* __restrict__ den2,
    float* __restrict__ den3, float* __restrict__ sc1,
    float* __restrict__ sc2, float* __restrict__ sc3, int E) {
    __shared__ unsigned short lK[64 * 128];  // 16 KB k tile, bf16, XOR-swizzled
    const int t = threadIdx.x;
    const int e0 = blockIdx.x * 64;
    const int lane = t & 63, wid = t >> 6;
    const int lm = lane & 15, lq = lane >> 4;
    const int wm = wid * 16;

    bf16x8 a[4];
#pragma unroll
    for (int s = 0; s < 4; ++s) {
        int e = e0 + wm + lm;
        if (e >= E) e = E - 1;
        a[s] = cvt8(eh + (size_t)e * FD + s * 32 + lq * 8);
    }
    f32x4 acc[8];
#pragma unroll
    for (int nt = 0; nt < 8; ++nt) {
        float b = bk[nt * 16 + lm];
        acc[nt][0] = b; acc[nt][1] = b; acc[nt][2] = b; acc[nt][3] = b;
    }
#pragma unroll
    for (int s = 0; s < 4; ++s)
#pragma unroll
        for (int nt = 0; nt < 8; ++nt) {
            bf16x8 bf = *(const bf16x8*)(Wkb + (nt * 16 + lm) * FD + s * 32 + lq * 8);
            acc[nt] = __builtin_amdgcn_mfma_f32_16x16x32_bf16(
                a[s], bf, acc[nt], 0, 0, 0);
        }
    // k tile -> LDS (bf16), swizzle: block' = (n>>3) ^ (m&7)
#pragma unroll
    for (int nt = 0; nt < 8; ++nt)
#pragma unroll
        for (int r = 0; r < 4; ++r) {
            int m = wm + lq * 4 + r;
            int n = nt * 16 + lm;
            int swb = (n >> 3) ^ (m & 7);
            lK[m * 128 + swb * 8 + (n & 7)] = bf_rne(acc[nt][r]);
        }
    __syncthreads();

    const float lamv = lam[0];
#pragma unroll
    for (int i = 0; i < 2; ++i) {
        int p = i * 256 + t;      // 64 edges * 8 heads = 512 items
        int el = p >> 3, h = p & 7;
        int e = e0 + el;
        if (e >= E) continue;
        int si = src[e], di = dst[e];
        const unsigned short* qsp = qb + (size_t)si * FD + h * 16;
        const unsigned short* qdp = qb + (size_t)di * FD + h * 16;
        bf16x8 qs0 = *(const bf16x8*)qsp;
        bf16x8 qs1 = *(const bf16x8*)(qsp + 8);
        bf16x8 qd0 = *(const bf16x8*)qdp;
        bf16x8 qd1 = *(const bf16x8*)(qdp + 8);
        int swb0 = (2 * h) ^ (el & 7), swb1 = (2 * h + 1) ^ (el & 7);
        bf16x8 k0 = *(const bf16x8*)(lK + el * 128 + swb0 * 8);
        bf16x8 k1 = *(const bf16x8*)(lK + el * 128 + swb1 * 8);
        float pin = 0.f, pot = 0.f, pdg = 0.f;
#pragma unroll
        for (int j = 0; j < 8; ++j) {
            float qsf = bf_to_f((unsigned short)qs0[j]);
            float qdf = bf_to_f((unsigned short)qd0[j]);
            float kf = bf_to_f((unsigned short)k0[j]);
            pin += qsf * kf; pot += qdf * kf; pdg += qsf * qdf;
        }
#pragma unroll
        for (int j = 0; j < 8; ++j) {
            float qsf = bf_to_f((unsigned short)qs1[j]);
            float qdf = bf_to_f((unsigned short)qd1[j]);
            float kf = bf_to_f((unsigned short)k1[j]);
            pin += qsf * kf; pot += qdf * kf; pdg += qsf * qdf;
        }
        float att = __expf(lamv * __logf(distance[e]));
        float e1 = __expf(pin * SCALE);
        float e2 = __expf(pot * SCALE);
        float e3 = __expf(pdg * SCALE);
        int nb = di * H + h;  // [N][H]: 8 heads of an edge share one 32B sector
        atomicAdd(den1 + nb, e1); atomicAdd(sc1 + nb, e1 * att);
        atomicAdd(den2 + nb, e2); atomicAdd(sc2 + nb, e2 * att);
        atomicAdd(den3 + nb, e3); atomicAdd(sc3 + nb, e3 * att);
    }
}

// ---- per (node,head): ssum = s1/d1 + s2/d2 + s3/d3 ----
__global__ __launch_bounds__(256) void combine_kernel(
    const float* __restrict__ den1, const float* __restrict__ den2,
    const float* __restrict__ den3, const float* __restrict__ sc1,
    const float* __restrict__ sc2, const float* __restrict__ sc3,
    float* __restrict__ ssum, int NH) {
    int i = blockIdx.x * 256 + threadIdx.x;
    if (i >= NH) return;
    float r = 0.f;
    float d1 = den1[i]; if (d1 != 0.f) r += sc1[i] / d1;
    float d2 = den2[i]; if (d2 != 0.f) r += sc2[i] / d2;
    float d3 = den3[i]; if (d3 != 0.f) r += sc3[i] / d3;
    ssum[i] = r;
}

// ---- out = leaky_relu( (ssum*v) @ Wo.T + bo ), MFMA, 64-row tile ----
__global__ __launch_bounds__(256) void out_kernel(
    const float* __restrict__ v, const float* __restrict__ ssum,
    const unsigned short* __restrict__ Wob, const float* __restrict__ bo,
    float* __restrict__ out, int Nrows) {
    const int t = threadIdx.x;
    const int lane = t & 63, wid = t >> 6;
    const int lm = lane & 15, lq = lane >> 4;
    const int r0 = blockIdx.x * 64 + wid * 16;

    bf16x8 a[4];
#pragma unroll
    for (int s = 0; s < 4; ++s) {
        int r = r0 + lm;
        if (r >= Nrows) r = Nrows - 1;
        int k0 = s * 32 + lq * 8;
        float sc = ssum[r * H + (k0 >> 4)];  // [N][H]
        const float* p = v + (size_t)r * FD + k0;
        float4 x = *(const float4*)p;
        float4 y = *(const float4*)(p + 4);
        bf16x8 f;
        f[0] = bf_rne(x.x * sc); f[1] = bf_rne(x.y * sc);
        f[2] = bf_rne(x.z * sc); f[3] = bf_rne(x.w * sc);
        f[4] = bf_rne(y.x * sc); f[5] = bf_rne(y.y * sc);
        f[6] = bf_rne(y.z * sc); f[7] = bf_rne(y.w * sc);
        a[s] = f;
    }
    f32x4 acc[8];
#pragma unroll
    for (int nt = 0; nt < 8; ++nt) {
        float b = bo[nt * 16 + lm];
        acc[nt][0] = b; acc[nt][1] = b; acc[nt][2] = b; acc[nt][3] = b;
    }
#pragma unroll
    for (int s = 0; s < 4; ++s)
#pragma unroll
        for (int nt = 0; nt < 8; ++nt) {
            bf16x8 bf = *(const bf16x8*)(Wob + (nt * 16 + lm) * FD + s * 32 + lq * 8);
            acc[nt] = __builtin_amdgcn_mfma_f32_16x16x32_bf16(
                a[s], bf, acc[nt], 0, 0, 0);
        }
#pragma unroll
    for (int nt = 0; nt < 8; ++nt)
#pragma unroll
        for (int r = 0; r < 4; ++r) {
            int row = r0 + lq * 4 + r;
            if (row >= Nrows) continue;
            int col = nt * 16 + lm;
            float x = acc[nt][r];
            out[(size_t)row * FD + col] = x > 0.f ? x : 0.1f * x;
        }
}

extern "C" void kernel_launch(void* const* d_in, const int* in_sizes, int n_in,
                              void* d_out, int out_size, void* d_ws,
                              size_t ws_size, hipStream_t stream) {
    (void)n_in; (void)out_size; (void)ws_size;
    const float* node_h   = (const float*)d_in[0];
    const float* edge_h   = (const float*)d_in[1];
    const float* distance = (const float*)d_in[2];
    const float* Wq = (const float*)d_in[3];
    const float* bq = (const float*)d_in[4];
    const float* Wk = (const float*)d_in[5];
    const float* bk = (const float*)d_in[6];
    const float* Wv = (const float*)d_in[7];
    const float* bv = (const float*)d_in[8];
    const float* Wo = (const float*)d_in[9];
    const float* bo = (const float*)d_in[10];
    const float* lam = (const float*)d_in[11];
    const int* src = (const int*)d_in[12];
    const int* dst = (const int*)d_in[13];

    int N = in_sizes[0] / FD;
    int E = in_sizes[1] / FD;
    int NH = N * H;

    char* ws = (char*)d_ws;
    unsigned short* Wqb = (unsigned short*)ws; ws += FD * FD * 2;
    unsigned short* Wkb = (unsigned short*)ws; ws += FD * FD * 2;
    unsigned short* Wvb = (unsigned short*)ws; ws += FD * FD * 2;
    unsigned short* Wob = (unsigned short*)ws; ws += FD * FD * 2;
    unsigned short* qb  = (unsigned short*)ws; ws += (size_t)N * FD * 2;
    float* v    = (float*)ws; ws += (size_t)N * FD * 4;
    char* zero_base = ws;
    float* den1 = (float*)ws; ws += (size_t)NH * 4;
    float* den2 = (float*)ws; ws += (size_t)NH * 4;
    float* den3 = (float*)ws; ws += (size_t)NH * 4;
    float* sc1  = (float*)ws; ws += (size_t)NH * 4;
    float* sc2  = (float*)ws; ws += (size_t)NH * 4;
    float* sc3  = (float*)ws; ws += (size_t)NH * 4;
    float* ssum = (float*)ws; ws += (size_t)NH * 4;

    hipMemsetAsync(zero_base, 0, (size_t)6 * NH * 4, stream);

    prep_kernel<<<16, 256, 0, stream>>>(Wq, Wk, Wv, Wo, Wqb, Wkb, Wvb, Wob);

    int nb = (N + 63) / 64;
    qv_kernel<<<nb, 256, 0, stream>>>(node_h, Wqb, Wvb, bq, bv, qb, v, N);

    int ebl = (E + 63) / 64;
    edge_kernel<<<ebl, 256, 0, stream>>>(edge_h, Wkb, bk, qb, src, dst,
                                         distance, lam,
                                         den1, den2, den3, sc1, sc2, sc3, E);

    combine_kernel<<<(NH + 255) / 256, 256, 0, stream>>>(
        den1, den2, den3, sc1, sc2, sc3, ssum, NH);

    out_kernel<<<nb, 256, 0, stream>>>(v, ssum, Wob, bo, (float*)d_out, N);
}